// Round 3
// baseline (1560.871 us; speedup 1.0000x reference)
//
#include <hip/hip_runtime.h>
#include <hip/hip_bf16.h>

#define DEV __device__ __forceinline__

typedef short short8 __attribute__((ext_vector_type(8)));
typedef _Float16 h8 __attribute__((ext_vector_type(8)));
typedef _Float16 h2 __attribute__((ext_vector_type(2)));
typedef float f32x4 __attribute__((ext_vector_type(4)));
typedef float v2f __attribute__((ext_vector_type(2)));
typedef unsigned short u16;

constexpr int T_ = 1024, B_ = 256, N_ = T_ * B_, D_ = 128;
constexpr int FS = 48;   // feat f16 row: 0-17 data, 18-23 zero, 24-41 data, 42-47 zero
constexpr int SEGCAP = 160;
constexpr unsigned DEADT = 0xFFFFu;

DEV u16 f2b(float f) {
  unsigned u = __float_as_uint(f);
  return (u16)((u + 0x7fffu + ((u >> 16) & 1u)) >> 16);  // RNE
}
DEV v2f fma2(v2f a, v2f b, v2f c) {
  v2f r; r.x = fmaf(a.x, b.x, c.x); r.y = fmaf(a.y, b.y, c.y); return r;
}

#if __has_builtin(__builtin_amdgcn_exp2f)
#define EXP2F __builtin_amdgcn_exp2f
#else
#define EXP2F __exp2f
#endif
#if __has_builtin(__builtin_amdgcn_rcpf)
#define RCPF __builtin_amdgcn_rcpf
#else
#define RCPF(x) (1.0f / (x))
#endif
DEV float sigf(float x) { return RCPF(1.0f + EXP2F(x * -1.44269504f)); }
DEV float tanhf_(float x) {
  return fmaf(RCPF(1.0f + EXP2F(x * -2.88539008f)), 2.0f, -1.0f);
}

// ---------------- prep: weight conversion ----------------
__global__ void prep_kernel(const float* W1, const float* W2, const float* W3,
                            const float* W4, const float* emb, const float* msgW,
                            const float* msgb, const float* Wih, const float* Whh,
                            const float* bih, const float* bhh, u16* w1p, u16* w2b,
                            u16* w3b, u16* w4b, float* msgtab, _Float16* wfull,
                            float* biass) {
  int i0 = blockIdx.x * blockDim.x + threadIdx.x;
  int st = gridDim.x * blockDim.x;
  for (int i = i0; i < 256 * 32; i += st) {  // W1 padded [256][32]
    int r = i >> 5, k = i & 31;
    w1p[i] = (k < 9) ? f2b(W1[r * 9 + k]) : (u16)0;
  }
  for (int i = i0; i < 256 * 256; i += st) w2b[i] = f2b(W2[i]);
  for (int i = i0; i < 128 * 256; i += st) w3b[i] = f2b(W3[i]);
  for (int i = i0; i < 16 * 128; i += st) w4b[i] = f2b(W4[i]);
  for (int i = i0; i < 256; i += st) {  // msgtab[v][j] = relu(emb[v]·msgW[j]+b[j])
    int v = i >> 4, j = i & 15;
    float s = msgb[j];
    for (int k = 0; k < 16; ++k) s += emb[v * 16 + k] * msgW[j * 16 + k];
    msgtab[i] = s > 0.f ? s : 0.f;
  }
  // wfull[c][192]: k<128 = Whh[c][k]; k=128+p = Wih' per FS layout; else 0
  for (int i = i0; i < 512 * 192; i += st) {
    int c = i / 192, k = i % 192;
    float v;
    if (k < 128) v = Whh[(size_t)c * 128 + k];
    else {
      int p = k - 128;
      if (p < 18) v = Wih[(size_t)c * 36 + p];
      else if (p >= 24 && p < 42) v = Wih[(size_t)c * 36 + p - 6];
      else v = 0.f;
    }
    wfull[i] = (_Float16)v;
  }
  for (int i = i0; i < 512; i += st) biass[i] = bih[i] + bhh[i];
}

// ---------------- seg_scan: split each row's timeline into done-segments ----------------
// segq[(b*16+slot)*SEGCAP + j] = t0 | (len<<10); nq[b*16+slot] = count
__global__ void seg_scan_kernel(const float* done, unsigned* segq, int* nq) {
  int b = blockIdx.x * blockDim.x + threadIdx.x;
  if (b >= B_) return;
  int sums[16], cnts[16];
#pragma unroll
  for (int j = 0; j < 16; ++j) { sums[j] = 0; cnts[j] = 0; }
  int t0 = 0;
  for (int t = 1; t <= T_; ++t) {
    bool bd = (t == T_) || (done[(size_t)t * B_ + b] != 0.0f);
    if (!bd) continue;
    int len = t - t0;
    int m = 0, best = (cnts[0] >= SEGCAP) ? 0x7fffffff : sums[0];
#pragma unroll
    for (int j = 1; j < 16; ++j) {
      int v = (cnts[j] >= SEGCAP) ? 0x7fffffff : sums[j];
      if (v < best) { best = v; m = j; }
    }
    int cm = 0;
#pragma unroll
    for (int j = 0; j < 16; ++j) cm = (j == m) ? cnts[j] : cm;
    segq[((size_t)b * 16 + m) * SEGCAP + cm] = (unsigned)t0 | ((unsigned)len << 10);
#pragma unroll
    for (int j = 0; j < 16; ++j) {
      sums[j] += (j == m) ? len : 0;
      cnts[j] += (j == m) ? 1 : 0;
    }
    t0 = t;
  }
#pragma unroll
  for (int j = 0; j < 16; ++j) nq[b * 16 + j] = cnts[j];
}

// ---------------- encoder: 64-row blocks, bf16 MFMA MLP (unchanged) ----------------
template <int K, int OUTN, bool SWZIN>
DEV void mlp_layer(const u16* Ain, u16* Aout, const u16* Wb, const float* bias,
                   int colbase, int NT, int lane) {
  constexpr int KT = K / 32;
  const int lr = lane & 15, lg = lane >> 4;
  for (int nt = 0; nt < NT; ++nt) {
    const int col = colbase + nt * 16 + lr;
    short8 bf[KT];
#pragma unroll
    for (int kt = 0; kt < KT; ++kt)
      bf[kt] = *(const short8*)(Wb + col * K + kt * 32 + lg * 8);
    const float bcol = bias[col];
#pragma unroll
    for (int mt = 0; mt < 4; ++mt) {
      f32x4 acc = {0.f, 0.f, 0.f, 0.f};
#pragma unroll
      for (int kt = 0; kt < KT; ++kt) {
        const int row = mt * 16 + lr;
        int kb = (kt * 32 + lg * 8) * 2;
        if (SWZIN) kb ^= (row & 7) << 4;
        const short8 af = *(const short8*)(Ain + row * K + (kb >> 1));
        acc = __builtin_amdgcn_mfma_f32_16x16x32_bf16(af, bf[kt], acc, 0, 0, 0);
      }
#pragma unroll
      for (int r = 0; r < 4; ++r) {
        const int row = mt * 16 + lg * 4 + r;
        float v = acc[r] + bcol;
        v = v > 0.f ? v : 0.f;
        const int kb = (col * 2) ^ ((row & 7) << 4);
        Aout[row * OUTN + (kb >> 1)] = f2b(v);
      }
    }
  }
}

__global__ __launch_bounds__(256) void enc_kernel(
    const float* image, const float* location, const int* message,
    const float* vb1, const float* vb2, const float* vb3, const float* vb4,
    const float* locW, const float* locb, const u16* w1p, const u16* w2b,
    const u16* w3b, const u16* w4b, const float* msgtab, _Float16* featf) {
  __shared__ __align__(16) u16 buf1[64 * 256];
  __shared__ __align__(16) u16 buf2[64 * 256];
  const int n0 = blockIdx.x * 64;
  const int tid = threadIdx.x;
  const int wave = tid >> 6, lane = tid & 63;

  for (int i = tid; i < 64 * 32; i += 256) {  // stage X/255 padded to K=32
    int r = i >> 5, k = i & 31;
    float v = (k < 9) ? image[(size_t)(n0 + r) * 9 + k] * (1.0f / 255.0f) : 0.0f;
    buf2[i] = f2b(v);
  }
  __syncthreads();
  mlp_layer<32, 256, false>(buf2, buf1, w1p, vb1, wave * 64, 4, lane);
  __syncthreads();
  mlp_layer<256, 256, true>(buf1, buf2, w2b, vb2, wave * 64, 4, lane);
  __syncthreads();
  mlp_layer<256, 128, true>(buf2, buf1, w3b, vb3, wave * 32, 2, lane);
  __syncthreads();
  {  // 128->16
    const int lr = lane & 15, lg = lane >> 4;
    const int col = lr;
    short8 bfr[4];
#pragma unroll
    for (int kt = 0; kt < 4; ++kt)
      bfr[kt] = *(const short8*)(w4b + col * 128 + kt * 32 + lg * 8);
    f32x4 acc = {0.f, 0.f, 0.f, 0.f};
#pragma unroll
    for (int kt = 0; kt < 4; ++kt) {
      const int row = wave * 16 + lr;
      const int kb = ((kt * 32 + lg * 8) * 2) ^ ((row & 7) << 4);
      const short8 af = *(const short8*)(buf1 + row * 128 + (kb >> 1));
      acc = __builtin_amdgcn_mfma_f32_16x16x32_bf16(af, bfr[kt], acc, 0, 0, 0);
    }
    const float bcol = vb4[col];
#pragma unroll
    for (int r = 0; r < 4; ++r) {
      const int row = wave * 16 + lg * 4 + r;
      float v = acc[r] + bcol;
      v = v > 0.f ? v : 0.f;
      featf[(size_t)(n0 + row) * FS + col] = (_Float16)v;
    }
  }
  if (tid < 64) {  // loc + msg features, zero pads
    const int n = n0 + tid;
    _Float16* fr = featf + (size_t)n * FS;
#pragma unroll
    for (int j = 0; j < 6; ++j) fr[18 + j] = (_Float16)0.f;
#pragma unroll
    for (int j = 0; j < 6; ++j) fr[42 + j] = (_Float16)0.f;
    const float x0 = location[(size_t)n * 2] * 0.2f;
    const float x1 = location[(size_t)n * 2 + 1] * 0.2f;
#pragma unroll
    for (int j = 0; j < 4; ++j) {
      const int pos = (j < 2) ? 16 + j : 22 + j;
      fr[pos] = (_Float16)fmaf(x0, locW[j * 2], fmaf(x1, locW[j * 2 + 1], locb[j]));
    }
    const float* mrow = msgtab + message[n] * 16;
#pragma unroll
    for (int j = 0; j < 16; ++j) fr[26 + j] = (_Float16)mrow[j];
  }
}

// ---------------- LSTM: segment-parallel MFMA, 16 segment-slots per block ----------------
// A = [h(128) | feat(48) | 0(16)] per slot (16 rows), B = [Whh ; Wih'] (192x512).
// Wave w owns d in [w*16, w*16+16); tile g = gate g cols (g*128 + d) -> all 4
// gates of (row,d) land in one lane. Weights register-resident as B-fragments.
__global__ __launch_bounds__(512, 2) void lstm_seg_kernel(
    const _Float16* featf, const _Float16* wfull, const float* biass,
    const unsigned* segq, const int* nq, const float* h0, const float* c0,
    const float* done, _Float16* hidh) {
  __shared__ __align__(16) char abuf[2][16 * 384];
  __shared__ unsigned st_ti[2][16];  // t | (trans<<16) for current step
  __shared__ unsigned st_tn[2][16];  // t of next step (for feat prefetch)
  __shared__ int st_any[2];
  const int b = blockIdx.x;
  const int tid = threadIdx.x;
  const int wave = tid >> 6, l = tid & 63;
  const int lc = l & 15, lg = l >> 4;
  const int d = wave * 16 + lc;

  // B fragments: 4 gate tiles x 6 K-steps, register-resident
  h8 bf[4][6];
#pragma unroll
  for (int g = 0; g < 4; ++g) {
    const _Float16* wp = wfull + (size_t)(g * 128 + d) * 192;
#pragma unroll
    for (int kt = 0; kt < 6; ++kt)
      bf[g][kt] = *(const h8*)(wp + kt * 32 + lg * 8);
  }
  float bias[4];
#pragma unroll
  for (int g = 0; g < 4; ++g) bias[g] = biass[g * 128 + d];

  for (int i = tid; i < 2 * 16 * 384 / 4; i += 512) ((float*)abuf)[i] = 0.0f;

  // manager state (threads 0..15): regs describe step i+1 while processing step i
  unsigned t_nx = DEADT, rem_nx = 0, qw = 0xFFFFFFFFu;
  int qidx = 2, qn = 0;
  const unsigned* qbase = segq + ((size_t)b * 16 + (tid & 15)) * SEGCAP;
  if (tid < 16) {
    qn = nq[b * 16 + tid];
    unsigned q0 = (0 < qn) ? qbase[0] : 0xFFFFFFFFu;
    unsigned q1 = (1 < qn) ? qbase[1] : 0xFFFFFFFFu;
    unsigned t0v = DEADT, rem0 = 0;
    if (q0 != 0xFFFFFFFFu) { t0v = q0 & 1023u; rem0 = (q0 >> 10) & 2047u; }
    unsigned tr0 = (t0v == DEADT || rem0 == 1) ? 1u : 0u;
    unsigned tn1;
    if (t0v == DEADT) tn1 = DEADT;
    else if (rem0 > 1) tn1 = t0v + 1;
    else tn1 = (q1 == 0xFFFFFFFFu) ? DEADT : (q1 & 1023u);
    st_ti[0][tid] = t0v | (tr0 << 16);
    st_tn[0][tid] = tn1;
    if (t0v == DEADT) t_nx = DEADT;
    else if (rem0 > 1) { t_nx = t0v + 1; rem_nx = rem0 - 1; qw = q1; }
    else {
      if (q1 == 0xFFFFFFFFu) t_nx = DEADT;
      else {
        t_nx = q1 & 1023u; rem_nx = (q1 >> 10) & 2047u;
        qw = (qidx < qn) ? qbase[qidx] : 0xFFFFFFFFu;
        if (qidx < qn) ++qidx;
      }
    }
    if (tid == 0) st_any[0] = 1;
  }
  __syncthreads();

  // prologue: h0/c0 (slot 0 only, scaled by 1-done[0]), feat(t(0))
  const float m0 = 1.0f - done[b];
  if (tid < 128)
    *(_Float16*)(abuf[0] + 2 * tid) = (_Float16)(h0[(size_t)b * D_ + tid] * m0);
  float creg[4];
#pragma unroll
  for (int r = 0; r < 4; ++r) {
    const int row = lg * 4 + r;
    creg[r] = (row == 0) ? c0[(size_t)b * D_ + d] * m0 : 0.0f;
  }
  const int slot = (tid < 96) ? (tid / 6) : 0;
  const int ch = (tid < 96) ? (tid % 6) : 0;
  if (tid < 96) {
    unsigned tt = st_ti[0][slot] & 0xFFFFu;
    if (tt != DEADT) {
      uint4 fv = *(const uint4*)(featf + ((size_t)tt * B_ + b) * FS + ch * 8);
      int byte = (slot * 384 + 256 + ch * 16) ^ ((slot & 7) << 4);
      *(uint4*)(abuf[0] + byte) = fv;
    }
  }
  __syncthreads();

  int p = 0;
  for (int iter = 0; iter < 1100; ++iter) {
    if (!st_any[p]) break;
    // --- read phase: A-frags, per-row state, feat prefetch for step i+1 ---
    const char* bp = abuf[p];
    h8 af[6];
#pragma unroll
    for (int kt = 0; kt < 6; ++kt) {
      const int byte = (lc * 384 + ((kt * 32 + lg * 8) << 1)) ^ ((lc & 7) << 4);
      af[kt] = *(const h8*)(bp + byte);
    }
    unsigned sti[4];
#pragma unroll
    for (int r = 0; r < 4; ++r) sti[r] = st_ti[p][lg * 4 + r];
    uint4 fv = {0, 0, 0, 0};
    unsigned tnx = DEADT;
    if (tid < 96) {
      tnx = st_tn[p][slot];
      if (tnx != DEADT)
        fv = *(const uint4*)(featf + ((size_t)tnx * B_ + b) * FS + ch * 8);
    }
    // --- MFMA: gates = A @ B + bias ---
    f32x4 acc[4];
#pragma unroll
    for (int g = 0; g < 4; ++g) acc[g] = f32x4{bias[g], bias[g], bias[g], bias[g]};
#pragma unroll
    for (int kt = 0; kt < 6; ++kt)
#pragma unroll
      for (int g = 0; g < 4; ++g)
        acc[g] = __builtin_amdgcn_mfma_f32_16x16x32_f16(af[kt], bf[g][kt],
                                                        acc[g], 0, 0, 0);
    // --- nonlinearity + c/h update + writes into buf[p^1] ---
    char* bn = abuf[p ^ 1];
#pragma unroll
    for (int r = 0; r < 4; ++r) {
      const int row = lg * 4 + r;
      const float gi = sigf(acc[0][r]);
      const float gf = sigf(acc[1][r]);
      const float gg = tanhf_(acc[2][r]);
      const float go = sigf(acc[3][r]);
      const float cn = fmaf(gf, creg[r], gi * gg);
      const float hv = go * tanhf_(cn);
      const unsigned w = sti[r];
      const unsigned tt = w & 0xFFFFu;
      const bool tr = (w >> 16) != 0u;
      creg[r] = tr ? 0.0f : cn;
      *(_Float16*)(bn + ((row * 384 + 2 * d) ^ ((row & 7) << 4))) =
          (_Float16)(tr ? 0.0f : hv);
      if (tt != DEADT) hidh[((size_t)tt * B_ + b) * D_ + d] = (_Float16)hv;
    }
    if (tid < 96 && tnx != DEADT) {
      const int byte = (slot * 384 + 256 + ch * 16) ^ ((slot & 7) << 4);
      *(uint4*)(bn + byte) = fv;
    }
    // --- manager publish for step i+1, advance to i+2 ---
    {
      bool active = false;
      if (tid < 16) {
        const unsigned t_pub = t_nx;
        const unsigned trp = (t_pub == DEADT || rem_nx == 1) ? 1u : 0u;
        unsigned tn2;
        if (t_pub == DEADT) tn2 = DEADT;
        else if (rem_nx > 1) tn2 = t_pub + 1;
        else tn2 = (qw == 0xFFFFFFFFu) ? DEADT : (qw & 1023u);
        st_ti[p ^ 1][tid] = t_pub | (trp << 16);
        st_tn[p ^ 1][tid] = tn2;
        active = (t_pub != DEADT);
        if (t_pub != DEADT) {
          if (rem_nx > 1) { t_nx = t_pub + 1; rem_nx = rem_nx - 1; }
          else if (qw == 0xFFFFFFFFu) t_nx = DEADT;
          else {
            t_nx = qw & 1023u; rem_nx = (qw >> 10) & 2047u;
            qw = (qidx < qn) ? qbase[qidx] : 0xFFFFFFFFu;
            if (qidx < qn) ++qidx;
          }
        }
      }
      unsigned long long bal = __ballot(active);
      if (tid == 0) st_any[p ^ 1] = ((bal & 0xFFFFull) != 0ull) ? 1 : 0;
    }
    asm volatile("s_waitcnt lgkmcnt(0)" ::: "memory");
    __builtin_amdgcn_s_barrier();
    p ^= 1;
  }
}

// ---------------- heads: 4 lanes per row, shuffle-reduced (f16 hidden) ----------------
__global__ __launch_bounds__(256) void head_kernel(const _Float16* hidh,
                                                   const float* aW, const float* ab,
                                                   const float* hW, const float* hb,
                                                   const float* cW, const float* cb,
                                                   float* out) {
  const int tid = threadIdx.x;
  const int w = tid >> 6, l = tid & 63;
  const int r = blockIdx.x * 64 + w * 16 + (l >> 2);
  const int kq = (l & 3) * 32;
  const _Float16* hp = hidh + (size_t)r * D_ + kq;
  float hx[32];
#pragma unroll
  for (int q = 0; q < 4; ++q) {
    const uint4 u = *(const uint4*)(hp + q * 8);
#pragma unroll
    for (int e = 0; e < 4; ++e) {
      const h2 pr = __builtin_bit_cast(h2, ((const unsigned*)&u)[e]);
      hx[q * 8 + e * 2] = (float)pr.x;
      hx[q * 8 + e * 2 + 1] = (float)pr.y;
    }
  }
  float acc[22];
#pragma unroll
  for (int j = 0; j < 22; ++j) {
    const float* wr = (j < 5) ? (aW + j * D_) : (j < 21 ? (hW + (j - 5) * D_) : cW);
    v2f a = {0.f, 0.f};
#pragma unroll
    for (int q = 0; q < 16; ++q) {
      const v2f wv = *(const v2f*)(wr + kq + q * 2);
      const v2f hv = {hx[q * 2], hx[q * 2 + 1]};
      a = fma2(wv, hv, a);
    }
    acc[j] = a.x + a.y;
  }
#pragma unroll
  for (int j = 0; j < 22; ++j) {
    acc[j] += __shfl_xor(acc[j], 1);
    acc[j] += __shfl_xor(acc[j], 2);
  }
  const int q = l & 3;
  float* orow = out + (size_t)r * 22;
#pragma unroll
  for (int jj = 0; jj < 5; ++jj) {
    const int j = q + jj * 4;
    const float bias = (j < 5) ? ab[j] : (j < 21 ? hb[j - 5] : cb[0]);
    orow[j] = acc[j] + bias;
  }
  if (q < 2) {
    const int j = 20 + q;
    orow[j] = acc[j] + hb[j - 5];
  }
}

extern "C" void kernel_launch(void* const* d_in, const int* in_sizes, int n_in,
                              void* d_out, int out_size, void* d_ws, size_t ws_size,
                              hipStream_t stream) {
  const float* image = (const float*)d_in[0];
  const float* location = (const float*)d_in[1];
  const int* message = (const int*)d_in[2];
  const float* done = (const float*)d_in[3];
  const float* h0 = (const float*)d_in[4];
  const float* c0 = (const float*)d_in[5];
  const float* vW1 = (const float*)d_in[6];
  const float* vb1 = (const float*)d_in[7];
  const float* vW2 = (const float*)d_in[8];
  const float* vb2 = (const float*)d_in[9];
  const float* vW3 = (const float*)d_in[10];
  const float* vb3 = (const float*)d_in[11];
  const float* vW4 = (const float*)d_in[12];
  const float* vb4 = (const float*)d_in[13];
  const float* locW = (const float*)d_in[14];
  const float* locb = (const float*)d_in[15];
  const float* emb = (const float*)d_in[16];
  const float* msgW = (const float*)d_in[17];
  const float* msgb = (const float*)d_in[18];
  const float* Wih = (const float*)d_in[19];
  const float* Whh = (const float*)d_in[20];
  const float* bih = (const float*)d_in[21];
  const float* bhh = (const float*)d_in[22];
  const float* aW = (const float*)d_in[23];
  const float* ab = (const float*)d_in[24];
  const float* hW = (const float*)d_in[25];
  const float* hb = (const float*)d_in[26];
  const float* cW = (const float*)d_in[27];
  const float* cb = (const float*)d_in[28];

  char* ws = (char*)d_ws;
  size_t off = 0;
  auto alloc = [&](size_t bytes) {
    void* p = ws + off;
    off = (off + bytes + 255) & ~(size_t)255;
    return p;
  };
  _Float16* featf = (_Float16*)alloc((size_t)N_ * FS * 2);   // 25.2 MB
  _Float16* hidh = (_Float16*)alloc((size_t)N_ * D_ * 2);    // 67.1 MB
  u16* w1p = (u16*)alloc(256 * 32 * 2);
  u16* w2b = (u16*)alloc(256 * 256 * 2);
  u16* w3b = (u16*)alloc(128 * 256 * 2);
  u16* w4b = (u16*)alloc(16 * 128 * 2);
  float* msgtab = (float*)alloc(256 * 4);
  _Float16* wfull = (_Float16*)alloc(512 * 192 * 2);
  float* biass = (float*)alloc(512 * 4);
  unsigned* segq = (unsigned*)alloc((size_t)B_ * 16 * SEGCAP * 4);  // 2.6 MB
  int* nqA = (int*)alloc(B_ * 16 * 4);
  (void)in_sizes; (void)n_in; (void)out_size; (void)ws_size;

  prep_kernel<<<64, 256, 0, stream>>>(vW1, vW2, vW3, vW4, emb, msgW, msgb, Wih,
                                      Whh, bih, bhh, w1p, w2b, w3b, w4b, msgtab,
                                      wfull, biass);
  seg_scan_kernel<<<4, 64, 0, stream>>>(done, segq, nqA);
  enc_kernel<<<N_ / 64, 256, 0, stream>>>(image, location, message, vb1, vb2, vb3,
                                          vb4, locW, locb, w1p, w2b, w3b, w4b,
                                          msgtab, featf);
  lstm_seg_kernel<<<B_, 512, 0, stream>>>(featf, wfull, biass, segq, nqA, h0, c0,
                                          done, hidh);
  head_kernel<<<N_ / 64, 256, 0, stream>>>(hidh, aW, ab, hW, hb, cW, cb,
                                           (float*)d_out);
}

// Round 4
// 852.035 us; speedup vs baseline: 1.8319x; 1.8319x over previous
//
#include <hip/hip_runtime.h>
#include <hip/hip_bf16.h>

#define DEV __device__ __forceinline__

typedef short short8 __attribute__((ext_vector_type(8)));
typedef _Float16 h8 __attribute__((ext_vector_type(8)));
typedef _Float16 h2 __attribute__((ext_vector_type(2)));
typedef float f32x4 __attribute__((ext_vector_type(4)));
typedef float v2f __attribute__((ext_vector_type(2)));
typedef unsigned short u16;

constexpr int T_ = 1024, B_ = 256, N_ = T_ * B_, D_ = 128;
constexpr int FS = 48;   // feat f16 row: 0-17 data, 18-23 zero, 24-41 data, 42-47 zero
constexpr int SEGCAP = 160;
constexpr unsigned DEADT = 0xFFFFu;

DEV u16 f2b(float f) {
  unsigned u = __float_as_uint(f);
  return (u16)((u + 0x7fffu + ((u >> 16) & 1u)) >> 16);  // RNE
}
DEV v2f fma2(v2f a, v2f b, v2f c) {
  v2f r; r.x = fmaf(a.x, b.x, c.x); r.y = fmaf(a.y, b.y, c.y); return r;
}

#if __has_builtin(__builtin_amdgcn_exp2f)
#define EXP2F __builtin_amdgcn_exp2f
#else
#define EXP2F __exp2f
#endif
#if __has_builtin(__builtin_amdgcn_rcpf)
#define RCPF __builtin_amdgcn_rcpf
#else
#define RCPF(x) (1.0f / (x))
#endif
DEV float sigf(float x) { return RCPF(1.0f + EXP2F(x * -1.44269504f)); }
DEV float tanhf_(float x) {
  return fmaf(RCPF(1.0f + EXP2F(x * -2.88539008f)), 2.0f, -1.0f);
}

// ---------------- prep: weight conversion ----------------
__global__ void prep_kernel(const float* W1, const float* W2, const float* W3,
                            const float* W4, const float* emb, const float* msgW,
                            const float* msgb, const float* Wih, const float* Whh,
                            const float* bih, const float* bhh, u16* w1p, u16* w2b,
                            u16* w3b, u16* w4b, float* msgtab, _Float16* wfull,
                            float* biass) {
  int i0 = blockIdx.x * blockDim.x + threadIdx.x;
  int st = gridDim.x * blockDim.x;
  for (int i = i0; i < 256 * 32; i += st) {  // W1 padded [256][32]
    int r = i >> 5, k = i & 31;
    w1p[i] = (k < 9) ? f2b(W1[r * 9 + k]) : (u16)0;
  }
  for (int i = i0; i < 256 * 256; i += st) w2b[i] = f2b(W2[i]);
  for (int i = i0; i < 128 * 256; i += st) w3b[i] = f2b(W3[i]);
  for (int i = i0; i < 16 * 128; i += st) w4b[i] = f2b(W4[i]);
  for (int i = i0; i < 256; i += st) {  // msgtab[v][j] = relu(emb[v]·msgW[j]+b[j])
    int v = i >> 4, j = i & 15;
    float s = msgb[j];
    for (int k = 0; k < 16; ++k) s += emb[v * 16 + k] * msgW[j * 16 + k];
    msgtab[i] = s > 0.f ? s : 0.f;
  }
  // wfull[c][192]: k<128 = Whh[c][k]; k=128+p = Wih' per FS layout; else 0
  for (int i = i0; i < 512 * 192; i += st) {
    int c = i / 192, k = i % 192;
    float v;
    if (k < 128) v = Whh[(size_t)c * 128 + k];
    else {
      int p = k - 128;
      if (p < 18) v = Wih[(size_t)c * 36 + p];
      else if (p >= 24 && p < 42) v = Wih[(size_t)c * 36 + p - 6];
      else v = 0.f;
    }
    wfull[i] = (_Float16)v;
  }
  for (int i = i0; i < 512; i += st) biass[i] = bih[i] + bhh[i];
}

// ---------------- seg_scan: one block per batch row, parallel break-gather ----------------
// segq[(b*16+slot)*SEGCAP + j] = t0 | (len<<10); nq[b*16+slot] = count
__global__ __launch_bounds__(64) void seg_scan_kernel(const float* done,
                                                      unsigned* segq, int* nq) {
  __shared__ unsigned short brkpos[1024];
  __shared__ int lcnt[64];
  __shared__ int nb_sh;
  const int b = blockIdx.x;
  const int l = threadIdx.x;

  // lane l covers t in [l*16, l*16+16); all 1024 loads issued independently
  unsigned mask = 0;
#pragma unroll
  for (int j = 0; j < 16; ++j) {
    const int t = l * 16 + j;
    const float dv = (t == 0) ? 0.0f : done[(size_t)t * B_ + b];
    mask |= (dv != 0.0f) ? (1u << j) : 0u;
  }
  lcnt[l] = __popc(mask);
  __syncthreads();
  if (l == 0) {
    int acc = 0;
    for (int i = 0; i < 64; ++i) { const int c = lcnt[i]; lcnt[i] = acc; acc += c; }
    nb_sh = acc;
  }
  __syncthreads();
  {
    int off = lcnt[l];
    unsigned mm = mask;
    while (mm) {
      const int j = __builtin_ctz(mm);
      mm &= mm - 1;
      brkpos[off++] = (unsigned short)(l * 16 + j);
    }
  }
  __syncthreads();
  if (l == 0) {
    const int nb = nb_sh;
    int sums[16], cnts[16];
#pragma unroll
    for (int j = 0; j < 16; ++j) { sums[j] = 0; cnts[j] = 0; }
    int t0 = 0;
    for (int s = 0; s <= nb; ++s) {
      const int t1 = (s < nb) ? (int)brkpos[s] : T_;
      const int len = t1 - t0;
      int m = 0, best = (cnts[0] >= SEGCAP) ? 0x7fffffff : sums[0];
#pragma unroll
      for (int j = 1; j < 16; ++j) {
        const int v = (cnts[j] >= SEGCAP) ? 0x7fffffff : sums[j];
        if (v < best) { best = v; m = j; }
      }
      int cm = 0;
#pragma unroll
      for (int j = 0; j < 16; ++j) cm = (j == m) ? cnts[j] : cm;
      segq[((size_t)b * 16 + m) * SEGCAP + cm] =
          (unsigned)t0 | ((unsigned)len << 10);
#pragma unroll
      for (int j = 0; j < 16; ++j) {
        sums[j] += (j == m) ? len : 0;
        cnts[j] += (j == m) ? 1 : 0;
      }
      t0 = t1;
    }
#pragma unroll
    for (int j = 0; j < 16; ++j) nq[b * 16 + j] = cnts[j];
  }
}

// ---------------- encoder: 64-row blocks, bf16 MFMA MLP (unchanged) ----------------
template <int K, int OUTN, bool SWZIN>
DEV void mlp_layer(const u16* Ain, u16* Aout, const u16* Wb, const float* bias,
                   int colbase, int NT, int lane) {
  constexpr int KT = K / 32;
  const int lr = lane & 15, lg = lane >> 4;
  for (int nt = 0; nt < NT; ++nt) {
    const int col = colbase + nt * 16 + lr;
    short8 bf[KT];
#pragma unroll
    for (int kt = 0; kt < KT; ++kt)
      bf[kt] = *(const short8*)(Wb + col * K + kt * 32 + lg * 8);
    const float bcol = bias[col];
#pragma unroll
    for (int mt = 0; mt < 4; ++mt) {
      f32x4 acc = {0.f, 0.f, 0.f, 0.f};
#pragma unroll
      for (int kt = 0; kt < KT; ++kt) {
        const int row = mt * 16 + lr;
        int kb = (kt * 32 + lg * 8) * 2;
        if (SWZIN) kb ^= (row & 7) << 4;
        const short8 af = *(const short8*)(Ain + row * K + (kb >> 1));
        acc = __builtin_amdgcn_mfma_f32_16x16x32_bf16(af, bf[kt], acc, 0, 0, 0);
      }
#pragma unroll
      for (int r = 0; r < 4; ++r) {
        const int row = mt * 16 + lg * 4 + r;
        float v = acc[r] + bcol;
        v = v > 0.f ? v : 0.f;
        const int kb = (col * 2) ^ ((row & 7) << 4);
        Aout[row * OUTN + (kb >> 1)] = f2b(v);
      }
    }
  }
}

__global__ __launch_bounds__(256) void enc_kernel(
    const float* image, const float* location, const int* message,
    const float* vb1, const float* vb2, const float* vb3, const float* vb4,
    const float* locW, const float* locb, const u16* w1p, const u16* w2b,
    const u16* w3b, const u16* w4b, const float* msgtab, _Float16* featf) {
  __shared__ __align__(16) u16 buf1[64 * 256];
  __shared__ __align__(16) u16 buf2[64 * 256];
  const int n0 = blockIdx.x * 64;
  const int tid = threadIdx.x;
  const int wave = tid >> 6, lane = tid & 63;

  for (int i = tid; i < 64 * 32; i += 256) {  // stage X/255 padded to K=32
    int r = i >> 5, k = i & 31;
    float v = (k < 9) ? image[(size_t)(n0 + r) * 9 + k] * (1.0f / 255.0f) : 0.0f;
    buf2[i] = f2b(v);
  }
  __syncthreads();
  mlp_layer<32, 256, false>(buf2, buf1, w1p, vb1, wave * 64, 4, lane);
  __syncthreads();
  mlp_layer<256, 256, true>(buf1, buf2, w2b, vb2, wave * 64, 4, lane);
  __syncthreads();
  mlp_layer<256, 128, true>(buf2, buf1, w3b, vb3, wave * 32, 2, lane);
  __syncthreads();
  {  // 128->16
    const int lr = lane & 15, lg = lane >> 4;
    const int col = lr;
    short8 bfr[4];
#pragma unroll
    for (int kt = 0; kt < 4; ++kt)
      bfr[kt] = *(const short8*)(w4b + col * 128 + kt * 32 + lg * 8);
    f32x4 acc = {0.f, 0.f, 0.f, 0.f};
#pragma unroll
    for (int kt = 0; kt < 4; ++kt) {
      const int row = wave * 16 + lr;
      const int kb = ((kt * 32 + lg * 8) * 2) ^ ((row & 7) << 4);
      const short8 af = *(const short8*)(buf1 + row * 128 + (kb >> 1));
      acc = __builtin_amdgcn_mfma_f32_16x16x32_bf16(af, bfr[kt], acc, 0, 0, 0);
    }
    const float bcol = vb4[col];
#pragma unroll
    for (int r = 0; r < 4; ++r) {
      const int row = wave * 16 + lg * 4 + r;
      float v = acc[r] + bcol;
      v = v > 0.f ? v : 0.f;
      featf[(size_t)(n0 + row) * FS + col] = (_Float16)v;
    }
  }
  if (tid < 64) {  // loc + msg features, zero pads
    const int n = n0 + tid;
    _Float16* fr = featf + (size_t)n * FS;
#pragma unroll
    for (int j = 0; j < 6; ++j) fr[18 + j] = (_Float16)0.f;
#pragma unroll
    for (int j = 0; j < 6; ++j) fr[42 + j] = (_Float16)0.f;
    const float x0 = location[(size_t)n * 2] * 0.2f;
    const float x1 = location[(size_t)n * 2 + 1] * 0.2f;
#pragma unroll
    for (int j = 0; j < 4; ++j) {
      const int pos = (j < 2) ? 16 + j : 22 + j;
      fr[pos] = (_Float16)fmaf(x0, locW[j * 2], fmaf(x1, locW[j * 2 + 1], locb[j]));
    }
    const float* mrow = msgtab + message[n] * 16;
#pragma unroll
    for (int j = 0; j < 16; ++j) fr[26 + j] = (_Float16)mrow[j];
  }
}

// ---------------- LSTM: segment-parallel MFMA, 16 segment-slots per block ----------------
// A = [h(128) | feat(48) | 0(16)] per slot (16 rows), B = [Whh ; Wih'] (192x512).
// Wave w owns d in [w*16, w*16+16); tile g = gate g cols (g*128 + d) -> all 4
// gates of (row,d) land in one lane. Weights register-resident as B-fragments.
__global__ __launch_bounds__(512, 2) void lstm_seg_kernel(
    const _Float16* featf, const _Float16* wfull, const float* biass,
    const unsigned* segq, const int* nq, const float* h0, const float* c0,
    const float* done, _Float16* hidh) {
  __shared__ __align__(16) char abuf[2][16 * 384];
  __shared__ unsigned st_ti[2][16];  // t | (trans<<16) for current step
  __shared__ unsigned st_tn[2][16];  // t of next step (for feat prefetch)
  __shared__ int st_any[2];
  const int b = blockIdx.x;
  const int tid = threadIdx.x;
  const int wave = tid >> 6, l = tid & 63;
  const int lc = l & 15, lg = l >> 4;
  const int d = wave * 16 + lc;

  // B fragments: 4 gate tiles x 6 K-steps, register-resident
  h8 bf[4][6];
#pragma unroll
  for (int g = 0; g < 4; ++g) {
    const _Float16* wp = wfull + (size_t)(g * 128 + d) * 192;
#pragma unroll
    for (int kt = 0; kt < 6; ++kt)
      bf[g][kt] = *(const h8*)(wp + kt * 32 + lg * 8);
  }
  float bias[4];
#pragma unroll
  for (int g = 0; g < 4; ++g) bias[g] = biass[g * 128 + d];

  for (int i = tid; i < 2 * 16 * 384 / 4; i += 512) ((float*)abuf)[i] = 0.0f;

  // manager state (threads 0..15): regs describe step i+1 while processing step i
  unsigned t_nx = DEADT, rem_nx = 0, qw = 0xFFFFFFFFu;
  int qidx = 2, qn = 0;
  const unsigned* qbase = segq + ((size_t)b * 16 + (tid & 15)) * SEGCAP;
  if (tid < 16) {
    qn = nq[b * 16 + tid];
    unsigned q0 = (0 < qn) ? qbase[0] : 0xFFFFFFFFu;
    unsigned q1 = (1 < qn) ? qbase[1] : 0xFFFFFFFFu;
    unsigned t0v = DEADT, rem0 = 0;
    if (q0 != 0xFFFFFFFFu) { t0v = q0 & 1023u; rem0 = (q0 >> 10) & 2047u; }
    unsigned tr0 = (t0v == DEADT || rem0 == 1) ? 1u : 0u;
    unsigned tn1;
    if (t0v == DEADT) tn1 = DEADT;
    else if (rem0 > 1) tn1 = t0v + 1;
    else tn1 = (q1 == 0xFFFFFFFFu) ? DEADT : (q1 & 1023u);
    st_ti[0][tid] = t0v | (tr0 << 16);
    st_tn[0][tid] = tn1;
    if (t0v == DEADT) t_nx = DEADT;
    else if (rem0 > 1) { t_nx = t0v + 1; rem_nx = rem0 - 1; qw = q1; }
    else {
      if (q1 == 0xFFFFFFFFu) t_nx = DEADT;
      else {
        t_nx = q1 & 1023u; rem_nx = (q1 >> 10) & 2047u;
        qw = (qidx < qn) ? qbase[qidx] : 0xFFFFFFFFu;
        if (qidx < qn) ++qidx;
      }
    }
    if (tid == 0) st_any[0] = 1;
  }
  __syncthreads();

  // prologue: h0/c0 (slot 0 only, scaled by 1-done[0]), feat(t(0))
  const float m0 = 1.0f - done[b];
  if (tid < 128)
    *(_Float16*)(abuf[0] + 2 * tid) = (_Float16)(h0[(size_t)b * D_ + tid] * m0);
  float creg[4];
#pragma unroll
  for (int r = 0; r < 4; ++r) {
    const int row = lg * 4 + r;
    creg[r] = (row == 0) ? c0[(size_t)b * D_ + d] * m0 : 0.0f;
  }
  const int slot = (tid < 96) ? (tid / 6) : 0;
  const int ch = (tid < 96) ? (tid % 6) : 0;
  if (tid < 96) {
    unsigned tt = st_ti[0][slot] & 0xFFFFu;
    if (tt != DEADT) {
      uint4 fv = *(const uint4*)(featf + ((size_t)tt * B_ + b) * FS + ch * 8);
      int byte = (slot * 384 + 256 + ch * 16) ^ ((slot & 7) << 4);
      *(uint4*)(abuf[0] + byte) = fv;
    }
  }
  __syncthreads();

  int p = 0;
  for (int iter = 0; iter < 1100; ++iter) {
    if (!st_any[p]) break;
    // --- read phase: A-frags, per-row state, feat prefetch for step i+1 ---
    const char* bp = abuf[p];
    h8 af[6];
#pragma unroll
    for (int kt = 0; kt < 6; ++kt) {
      const int byte = (lc * 384 + ((kt * 32 + lg * 8) << 1)) ^ ((lc & 7) << 4);
      af[kt] = *(const h8*)(bp + byte);
    }
    unsigned sti[4];
#pragma unroll
    for (int r = 0; r < 4; ++r) sti[r] = st_ti[p][lg * 4 + r];
    uint4 fv = {0, 0, 0, 0};
    unsigned tnx = DEADT;
    if (tid < 96) {
      tnx = st_tn[p][slot];
      if (tnx != DEADT)
        fv = *(const uint4*)(featf + ((size_t)tnx * B_ + b) * FS + ch * 8);
    }
    // --- MFMA: gates = A @ B + bias ---
    f32x4 acc[4];
#pragma unroll
    for (int g = 0; g < 4; ++g) acc[g] = f32x4{bias[g], bias[g], bias[g], bias[g]};
#pragma unroll
    for (int kt = 0; kt < 6; ++kt)
#pragma unroll
      for (int g = 0; g < 4; ++g)
        acc[g] = __builtin_amdgcn_mfma_f32_16x16x32_f16(af[kt], bf[g][kt],
                                                        acc[g], 0, 0, 0);
    // --- nonlinearity + c/h update + writes into buf[p^1] ---
    char* bn = abuf[p ^ 1];
#pragma unroll
    for (int r = 0; r < 4; ++r) {
      const int row = lg * 4 + r;
      const float gi = sigf(acc[0][r]);
      const float gf = sigf(acc[1][r]);
      const float gg = tanhf_(acc[2][r]);
      const float go = sigf(acc[3][r]);
      const float cn = fmaf(gf, creg[r], gi * gg);
      const float hv = go * tanhf_(cn);
      const unsigned w = sti[r];
      const unsigned tt = w & 0xFFFFu;
      const bool tr = (w >> 16) != 0u;
      creg[r] = tr ? 0.0f : cn;
      *(_Float16*)(bn + ((row * 384 + 2 * d) ^ ((row & 7) << 4))) =
          (_Float16)(tr ? 0.0f : hv);
      if (tt != DEADT) hidh[((size_t)tt * B_ + b) * D_ + d] = (_Float16)hv;
    }
    if (tid < 96 && tnx != DEADT) {
      const int byte = (slot * 384 + 256 + ch * 16) ^ ((slot & 7) << 4);
      *(uint4*)(bn + byte) = fv;
    }
    // --- manager publish for step i+1, advance to i+2 ---
    {
      bool active = false;
      if (tid < 16) {
        const unsigned t_pub = t_nx;
        const unsigned trp = (t_pub == DEADT || rem_nx == 1) ? 1u : 0u;
        unsigned tn2;
        if (t_pub == DEADT) tn2 = DEADT;
        else if (rem_nx > 1) tn2 = t_pub + 1;
        else tn2 = (qw == 0xFFFFFFFFu) ? DEADT : (qw & 1023u);
        st_ti[p ^ 1][tid] = t_pub | (trp << 16);
        st_tn[p ^ 1][tid] = tn2;
        active = (t_pub != DEADT);
        if (t_pub != DEADT) {
          if (rem_nx > 1) { t_nx = t_pub + 1; rem_nx = rem_nx - 1; }
          else if (qw == 0xFFFFFFFFu) t_nx = DEADT;
          else {
            t_nx = qw & 1023u; rem_nx = (qw >> 10) & 2047u;
            qw = (qidx < qn) ? qbase[qidx] : 0xFFFFFFFFu;
            if (qidx < qn) ++qidx;
          }
        }
      }
      unsigned long long bal = __ballot(active);
      if (tid == 0) st_any[p ^ 1] = ((bal & 0xFFFFull) != 0ull) ? 1 : 0;
    }
    asm volatile("s_waitcnt lgkmcnt(0)" ::: "memory");
    __builtin_amdgcn_s_barrier();
    p ^= 1;
  }
}

// ---------------- heads: 4 lanes per row, shuffle-reduced (f16 hidden) ----------------
__global__ __launch_bounds__(256) void head_kernel(const _Float16* hidh,
                                                   const float* aW, const float* ab,
                                                   const float* hW, const float* hb,
                                                   const float* cW, const float* cb,
                                                   float* out) {
  const int tid = threadIdx.x;
  const int w = tid >> 6, l = tid & 63;
  const int r = blockIdx.x * 64 + w * 16 + (l >> 2);
  const int kq = (l & 3) * 32;
  const _Float16* hp = hidh + (size_t)r * D_ + kq;
  float hx[32];
#pragma unroll
  for (int q = 0; q < 4; ++q) {
    const uint4 u = *(const uint4*)(hp + q * 8);
#pragma unroll
    for (int e = 0; e < 4; ++e) {
      const h2 pr = __builtin_bit_cast(h2, ((const unsigned*)&u)[e]);
      hx[q * 8 + e * 2] = (float)pr.x;
      hx[q * 8 + e * 2 + 1] = (float)pr.y;
    }
  }
  float acc[22];
#pragma unroll
  for (int j = 0; j < 22; ++j) {
    const float* wr = (j < 5) ? (aW + j * D_) : (j < 21 ? (hW + (j - 5) * D_) : cW);
    v2f a = {0.f, 0.f};
#pragma unroll
    for (int q = 0; q < 16; ++q) {
      const v2f wv = *(const v2f*)(wr + kq + q * 2);
      const v2f hv = {hx[q * 2], hx[q * 2 + 1]};
      a = fma2(wv, hv, a);
    }
    acc[j] = a.x + a.y;
  }
#pragma unroll
  for (int j = 0; j < 22; ++j) {
    acc[j] += __shfl_xor(acc[j], 1);
    acc[j] += __shfl_xor(acc[j], 2);
  }
  const int q = l & 3;
  float* orow = out + (size_t)r * 22;
#pragma unroll
  for (int jj = 0; jj < 5; ++jj) {
    const int j = q + jj * 4;
    const float bias = (j < 5) ? ab[j] : (j < 21 ? hb[j - 5] : cb[0]);
    orow[j] = acc[j] + bias;
  }
  if (q < 2) {
    const int j = 20 + q;
    orow[j] = acc[j] + hb[j - 5];
  }
}

extern "C" void kernel_launch(void* const* d_in, const int* in_sizes, int n_in,
                              void* d_out, int out_size, void* d_ws, size_t ws_size,
                              hipStream_t stream) {
  const float* image = (const float*)d_in[0];
  const float* location = (const float*)d_in[1];
  const int* message = (const int*)d_in[2];
  const float* done = (const float*)d_in[3];
  const float* h0 = (const float*)d_in[4];
  const float* c0 = (const float*)d_in[5];
  const float* vW1 = (const float*)d_in[6];
  const float* vb1 = (const float*)d_in[7];
  const float* vW2 = (const float*)d_in[8];
  const float* vb2 = (const float*)d_in[9];
  const float* vW3 = (const float*)d_in[10];
  const float* vb3 = (const float*)d_in[11];
  const float* vW4 = (const float*)d_in[12];
  const float* vb4 = (const float*)d_in[13];
  const float* locW = (const float*)d_in[14];
  const float* locb = (const float*)d_in[15];
  const float* emb = (const float*)d_in[16];
  const float* msgW = (const float*)d_in[17];
  const float* msgb = (const float*)d_in[18];
  const float* Wih = (const float*)d_in[19];
  const float* Whh = (const float*)d_in[20];
  const float* bih = (const float*)d_in[21];
  const float* bhh = (const float*)d_in[22];
  const float* aW = (const float*)d_in[23];
  const float* ab = (const float*)d_in[24];
  const float* hW = (const float*)d_in[25];
  const float* hb = (const float*)d_in[26];
  const float* cW = (const float*)d_in[27];
  const float* cb = (const float*)d_in[28];

  char* ws = (char*)d_ws;
  size_t off = 0;
  auto alloc = [&](size_t bytes) {
    void* p = ws + off;
    off = (off + bytes + 255) & ~(size_t)255;
    return p;
  };
  _Float16* featf = (_Float16*)alloc((size_t)N_ * FS * 2);   // 25.2 MB
  _Float16* hidh = (_Float16*)alloc((size_t)N_ * D_ * 2);    // 67.1 MB
  u16* w1p = (u16*)alloc(256 * 32 * 2);
  u16* w2b = (u16*)alloc(256 * 256 * 2);
  u16* w3b = (u16*)alloc(128 * 256 * 2);
  u16* w4b = (u16*)alloc(16 * 128 * 2);
  float* msgtab = (float*)alloc(256 * 4);
  _Float16* wfull = (_Float16*)alloc(512 * 192 * 2);
  float* biass = (float*)alloc(512 * 4);
  unsigned* segq = (unsigned*)alloc((size_t)B_ * 16 * SEGCAP * 4);  // 2.6 MB
  int* nqA = (int*)alloc(B_ * 16 * 4);
  (void)in_sizes; (void)n_in; (void)out_size; (void)ws_size;

  prep_kernel<<<64, 256, 0, stream>>>(vW1, vW2, vW3, vW4, emb, msgW, msgb, Wih,
                                      Whh, bih, bhh, w1p, w2b, w3b, w4b, msgtab,
                                      wfull, biass);
  seg_scan_kernel<<<B_, 64, 0, stream>>>(done, segq, nqA);
  enc_kernel<<<N_ / 64, 256, 0, stream>>>(image, location, message, vb1, vb2, vb3,
                                          vb4, locW, locb, w1p, w2b, w3b, w4b,
                                          msgtab, featf);
  lstm_seg_kernel<<<B_, 512, 0, stream>>>(featf, wfull, biass, segq, nqA, h0, c0,
                                          done, hidh);
  head_kernel<<<N_ / 64, 256, 0, stream>>>(hidh, aW, ab, hW, hb, cW, cb,
                                           (float*)d_out);
}

// Round 5
// 539.981 us; speedup vs baseline: 2.8906x; 1.5779x over previous
//
#include <hip/hip_runtime.h>
#include <hip/hip_bf16.h>

#define DEV __device__ __forceinline__

typedef short short8 __attribute__((ext_vector_type(8)));
typedef _Float16 h8 __attribute__((ext_vector_type(8)));
typedef _Float16 h2 __attribute__((ext_vector_type(2)));
typedef float f32x4 __attribute__((ext_vector_type(4)));
typedef unsigned short u16;

constexpr int T_ = 1024, B_ = 256, N_ = T_ * B_, D_ = 128;
constexpr int FS = 48;   // feat f16 row: 0-17 data, 18-23 zero, 24-41 data, 42-47 zero
constexpr int SEGCAP = 160;
constexpr unsigned DEADT = 0xFFFFu;

DEV u16 f2b(float f) {
  unsigned u = __float_as_uint(f);
  return (u16)((u + 0x7fffu + ((u >> 16) & 1u)) >> 16);  // RNE
}

#if __has_builtin(__builtin_amdgcn_exp2f)
#define EXP2F __builtin_amdgcn_exp2f
#else
#define EXP2F __exp2f
#endif
#if __has_builtin(__builtin_amdgcn_rcpf)
#define RCPF __builtin_amdgcn_rcpf
#else
#define RCPF(x) (1.0f / (x))
#endif
DEV float sigf(float x) { return RCPF(1.0f + EXP2F(x * -1.44269504f)); }
DEV float tanhf_(float x) {
  return fmaf(RCPF(1.0f + EXP2F(x * -2.88539008f)), 2.0f, -1.0f);
}

// ---------------- prep: weight conversion ----------------
__global__ void prep_kernel(const float* W1, const float* W2, const float* W3,
                            const float* W4, const float* emb, const float* msgW,
                            const float* msgb, const float* Wih, const float* Whh,
                            const float* bih, const float* bhh, const float* aW,
                            const float* ab, const float* hW, const float* hb,
                            const float* cW, const float* cb, u16* w1p, u16* w2b,
                            u16* w3b, u16* w4b, float* msgtab, _Float16* wfull,
                            float* biass, _Float16* w22, float* b22) {
  int i0 = blockIdx.x * blockDim.x + threadIdx.x;
  int st = gridDim.x * blockDim.x;
  for (int i = i0; i < 256 * 32; i += st) {  // W1 padded [256][32]
    int r = i >> 5, k = i & 31;
    w1p[i] = (k < 9) ? f2b(W1[r * 9 + k]) : (u16)0;
  }
  for (int i = i0; i < 256 * 256; i += st) w2b[i] = f2b(W2[i]);
  for (int i = i0; i < 128 * 256; i += st) w3b[i] = f2b(W3[i]);
  for (int i = i0; i < 16 * 128; i += st) w4b[i] = f2b(W4[i]);
  for (int i = i0; i < 256; i += st) {  // msgtab[v][j] = relu(emb[v]·msgW[j]+b[j])
    int v = i >> 4, j = i & 15;
    float s = msgb[j];
    for (int k = 0; k < 16; ++k) s += emb[v * 16 + k] * msgW[j * 16 + k];
    msgtab[i] = s > 0.f ? s : 0.f;
  }
  // wfull[c][192]: k<128 = Whh[c][k]; k=128+p = Wih' per FS layout; else 0
  for (int i = i0; i < 512 * 192; i += st) {
    int c = i / 192, k = i % 192;
    float v;
    if (k < 128) v = Whh[(size_t)c * 128 + k];
    else {
      int p = k - 128;
      if (p < 18) v = Wih[(size_t)c * 36 + p];
      else if (p >= 24 && p < 42) v = Wih[(size_t)c * 36 + p - 6];
      else v = 0.f;
    }
    wfull[i] = (_Float16)v;
  }
  for (int i = i0; i < 512; i += st) biass[i] = bih[i] + bhh[i];
  // w22[32][128]: rows 0-4 actor, 5-20 head, 21 critic, 22-31 zero
  for (int i = i0; i < 32 * 128; i += st) {
    int c = i >> 7, k = i & 127;
    float v = 0.f;
    if (c < 5) v = aW[c * 128 + k];
    else if (c < 21) v = hW[(c - 5) * 128 + k];
    else if (c == 21) v = cW[k];
    w22[i] = (_Float16)v;
  }
  for (int i = i0; i < 32; i += st) {
    float v = 0.f;
    if (i < 5) v = ab[i];
    else if (i < 21) v = hb[i - 5];
    else if (i == 21) v = cb[0];
    b22[i] = v;
  }
}

// ---------------- seg_scan: one block per batch row, parallel break-gather ----------------
// segq[(b*16+slot)*SEGCAP + j] = t0 | (len<<10); nq[b*16+slot] = count
__global__ __launch_bounds__(64) void seg_scan_kernel(const float* done,
                                                      unsigned* segq, int* nq) {
  __shared__ unsigned short brkpos[1024];
  __shared__ int lcnt[64];
  __shared__ int nb_sh;
  const int b = blockIdx.x;
  const int l = threadIdx.x;

  unsigned mask = 0;
#pragma unroll
  for (int j = 0; j < 16; ++j) {
    const int t = l * 16 + j;
    const float dv = (t == 0) ? 0.0f : done[(size_t)t * B_ + b];
    mask |= (dv != 0.0f) ? (1u << j) : 0u;
  }
  lcnt[l] = __popc(mask);
  __syncthreads();
  if (l == 0) {
    int acc = 0;
    for (int i = 0; i < 64; ++i) { const int c = lcnt[i]; lcnt[i] = acc; acc += c; }
    nb_sh = acc;
  }
  __syncthreads();
  {
    int off = lcnt[l];
    unsigned mm = mask;
    while (mm) {
      const int j = __builtin_ctz(mm);
      mm &= mm - 1;
      brkpos[off++] = (unsigned short)(l * 16 + j);
    }
  }
  __syncthreads();
  if (l == 0) {
    const int nb = nb_sh;
    int sums[16], cnts[16];
#pragma unroll
    for (int j = 0; j < 16; ++j) { sums[j] = 0; cnts[j] = 0; }
    int t0 = 0;
    for (int s = 0; s <= nb; ++s) {
      const int t1 = (s < nb) ? (int)brkpos[s] : T_;
      const int len = t1 - t0;
      int m = 0, best = (cnts[0] >= SEGCAP) ? 0x7fffffff : sums[0];
#pragma unroll
      for (int j = 1; j < 16; ++j) {
        const int v = (cnts[j] >= SEGCAP) ? 0x7fffffff : sums[j];
        if (v < best) { best = v; m = j; }
      }
      int cm = 0;
#pragma unroll
      for (int j = 0; j < 16; ++j) cm = (j == m) ? cnts[j] : cm;
      segq[((size_t)b * 16 + m) * SEGCAP + cm] =
          (unsigned)t0 | ((unsigned)len << 10);
#pragma unroll
      for (int j = 0; j < 16; ++j) {
        sums[j] += (j == m) ? len : 0;
        cnts[j] += (j == m) ? 1 : 0;
      }
      t0 = t1;
    }
#pragma unroll
    for (int j = 0; j < 16; ++j) nq[b * 16 + j] = cnts[j];
  }
}

// ---------------- encoder: 64-row blocks, bf16 MFMA MLP (unchanged) ----------------
template <int K, int OUTN, bool SWZIN>
DEV void mlp_layer(const u16* Ain, u16* Aout, const u16* Wb, const float* bias,
                   int colbase, int NT, int lane) {
  constexpr int KT = K / 32;
  const int lr = lane & 15, lg = lane >> 4;
  for (int nt = 0; nt < NT; ++nt) {
    const int col = colbase + nt * 16 + lr;
    short8 bf[KT];
#pragma unroll
    for (int kt = 0; kt < KT; ++kt)
      bf[kt] = *(const short8*)(Wb + col * K + kt * 32 + lg * 8);
    const float bcol = bias[col];
#pragma unroll
    for (int mt = 0; mt < 4; ++mt) {
      f32x4 acc = {0.f, 0.f, 0.f, 0.f};
#pragma unroll
      for (int kt = 0; kt < KT; ++kt) {
        const int row = mt * 16 + lr;
        int kb = (kt * 32 + lg * 8) * 2;
        if (SWZIN) kb ^= (row & 7) << 4;
        const short8 af = *(const short8*)(Ain + row * K + (kb >> 1));
        acc = __builtin_amdgcn_mfma_f32_16x16x32_bf16(af, bf[kt], acc, 0, 0, 0);
      }
#pragma unroll
      for (int r = 0; r < 4; ++r) {
        const int row = mt * 16 + lg * 4 + r;
        float v = acc[r] + bcol;
        v = v > 0.f ? v : 0.f;
        const int kb = (col * 2) ^ ((row & 7) << 4);
        Aout[row * OUTN + (kb >> 1)] = f2b(v);
      }
    }
  }
}

__global__ __launch_bounds__(256) void enc_kernel(
    const float* image, const float* location, const int* message,
    const float* vb1, const float* vb2, const float* vb3, const float* vb4,
    const float* locW, const float* locb, const u16* w1p, const u16* w2b,
    const u16* w3b, const u16* w4b, const float* msgtab, _Float16* featf) {
  __shared__ __align__(16) u16 buf1[64 * 256];
  __shared__ __align__(16) u16 buf2[64 * 256];
  const int n0 = blockIdx.x * 64;
  const int tid = threadIdx.x;
  const int wave = tid >> 6, lane = tid & 63;

  for (int i = tid; i < 64 * 32; i += 256) {  // stage X/255 padded to K=32
    int r = i >> 5, k = i & 31;
    float v = (k < 9) ? image[(size_t)(n0 + r) * 9 + k] * (1.0f / 255.0f) : 0.0f;
    buf2[i] = f2b(v);
  }
  __syncthreads();
  mlp_layer<32, 256, false>(buf2, buf1, w1p, vb1, wave * 64, 4, lane);
  __syncthreads();
  mlp_layer<256, 256, true>(buf1, buf2, w2b, vb2, wave * 64, 4, lane);
  __syncthreads();
  mlp_layer<256, 128, true>(buf2, buf1, w3b, vb3, wave * 32, 2, lane);
  __syncthreads();
  {  // 128->16
    const int lr = lane & 15, lg = lane >> 4;
    const int col = lr;
    short8 bfr[4];
#pragma unroll
    for (int kt = 0; kt < 4; ++kt)
      bfr[kt] = *(const short8*)(w4b + col * 128 + kt * 32 + lg * 8);
    f32x4 acc = {0.f, 0.f, 0.f, 0.f};
#pragma unroll
    for (int kt = 0; kt < 4; ++kt) {
      const int row = wave * 16 + lr;
      const int kb = ((kt * 32 + lg * 8) * 2) ^ ((row & 7) << 4);
      const short8 af = *(const short8*)(buf1 + row * 128 + (kb >> 1));
      acc = __builtin_amdgcn_mfma_f32_16x16x32_bf16(af, bfr[kt], acc, 0, 0, 0);
    }
    const float bcol = vb4[col];
#pragma unroll
    for (int r = 0; r < 4; ++r) {
      const int row = wave * 16 + lg * 4 + r;
      float v = acc[r] + bcol;
      v = v > 0.f ? v : 0.f;
      featf[(size_t)(n0 + row) * FS + col] = (_Float16)v;
    }
  }
  if (tid < 64) {  // loc + msg features, zero pads
    const int n = n0 + tid;
    _Float16* fr = featf + (size_t)n * FS;
#pragma unroll
    for (int j = 0; j < 6; ++j) fr[18 + j] = (_Float16)0.f;
#pragma unroll
    for (int j = 0; j < 6; ++j) fr[42 + j] = (_Float16)0.f;
    const float x0 = location[(size_t)n * 2] * 0.2f;
    const float x1 = location[(size_t)n * 2 + 1] * 0.2f;
#pragma unroll
    for (int j = 0; j < 4; ++j) {
      const int pos = (j < 2) ? 16 + j : 22 + j;
      fr[pos] = (_Float16)fmaf(x0, locW[j * 2], fmaf(x1, locW[j * 2 + 1], locb[j]));
    }
    const float* mrow = msgtab + message[n] * 16;
#pragma unroll
    for (int j = 0; j < 16; ++j) fr[26 + j] = (_Float16)mrow[j];
  }
}

// ---------------- LSTM: segment-parallel MFMA, 16 segment-slots per block ----------------
__global__ __launch_bounds__(512, 2) void lstm_seg_kernel(
    const _Float16* featf, const _Float16* wfull, const float* biass,
    const unsigned* segq, const int* nq, const float* h0, const float* c0,
    const float* done, _Float16* hidh) {
  __shared__ __align__(16) char abuf[2][16 * 384];
  __shared__ unsigned st_ti[2][16];  // t | (trans<<16) for current step
  __shared__ unsigned st_tn[2][16];  // t of next step (for feat prefetch)
  __shared__ int st_any[2];
  const int b = blockIdx.x;
  const int tid = threadIdx.x;
  const int wave = tid >> 6, l = tid & 63;
  const int lc = l & 15, lg = l >> 4;
  const int d = wave * 16 + lc;

  // B fragments: 4 gate tiles x 6 K-steps, register-resident
  h8 bf[4][6];
#pragma unroll
  for (int g = 0; g < 4; ++g) {
    const _Float16* wp = wfull + (size_t)(g * 128 + d) * 192;
#pragma unroll
    for (int kt = 0; kt < 6; ++kt)
      bf[g][kt] = *(const h8*)(wp + kt * 32 + lg * 8);
  }
  float bias[4];
#pragma unroll
  for (int g = 0; g < 4; ++g) bias[g] = biass[g * 128 + d];

  for (int i = tid; i < 2 * 16 * 384 / 4; i += 512) ((float*)abuf)[i] = 0.0f;

  // manager state (threads 0..15): regs describe step i+1 while processing step i
  unsigned t_nx = DEADT, rem_nx = 0, qw = 0xFFFFFFFFu;
  int qidx = 2, qn = 0;
  const unsigned* qbase = segq + ((size_t)b * 16 + (tid & 15)) * SEGCAP;
  if (tid < 16) {
    qn = nq[b * 16 + tid];
    unsigned q0 = (0 < qn) ? qbase[0] : 0xFFFFFFFFu;
    unsigned q1 = (1 < qn) ? qbase[1] : 0xFFFFFFFFu;
    unsigned t0v = DEADT, rem0 = 0;
    if (q0 != 0xFFFFFFFFu) { t0v = q0 & 1023u; rem0 = (q0 >> 10) & 2047u; }
    unsigned tr0 = (t0v == DEADT || rem0 == 1) ? 1u : 0u;
    unsigned tn1;
    if (t0v == DEADT) tn1 = DEADT;
    else if (rem0 > 1) tn1 = t0v + 1;
    else tn1 = (q1 == 0xFFFFFFFFu) ? DEADT : (q1 & 1023u);
    st_ti[0][tid] = t0v | (tr0 << 16);
    st_tn[0][tid] = tn1;
    if (t0v == DEADT) t_nx = DEADT;
    else if (rem0 > 1) { t_nx = t0v + 1; rem_nx = rem0 - 1; qw = q1; }
    else {
      if (q1 == 0xFFFFFFFFu) t_nx = DEADT;
      else {
        t_nx = q1 & 1023u; rem_nx = (q1 >> 10) & 2047u;
        qw = (qidx < qn) ? qbase[qidx] : 0xFFFFFFFFu;
        if (qidx < qn) ++qidx;
      }
    }
    if (tid == 0) st_any[0] = 1;
  }
  __syncthreads();

  // prologue: h0/c0 (slot 0 only, scaled by 1-done[0]), feat(t(0))
  const float m0 = 1.0f - done[b];
  if (tid < 128)
    *(_Float16*)(abuf[0] + 2 * tid) = (_Float16)(h0[(size_t)b * D_ + tid] * m0);
  float creg[4];
#pragma unroll
  for (int r = 0; r < 4; ++r) {
    const int row = lg * 4 + r;
    creg[r] = (row == 0) ? c0[(size_t)b * D_ + d] * m0 : 0.0f;
  }
  const int slot = (tid < 96) ? (tid / 6) : 0;
  const int ch = (tid < 96) ? (tid % 6) : 0;
  if (tid < 96) {
    unsigned tt = st_ti[0][slot] & 0xFFFFu;
    if (tt != DEADT) {
      uint4 fv = *(const uint4*)(featf + ((size_t)tt * B_ + b) * FS + ch * 8);
      int byte = (slot * 384 + 256 + ch * 16) ^ ((slot & 7) << 4);
      *(uint4*)(abuf[0] + byte) = fv;
    }
  }
  __syncthreads();

  int p = 0;
  for (int iter = 0; iter < 1100; ++iter) {
    if (!st_any[p]) break;
    const char* bp = abuf[p];
    h8 af[6];
#pragma unroll
    for (int kt = 0; kt < 6; ++kt) {
      const int byte = (lc * 384 + ((kt * 32 + lg * 8) << 1)) ^ ((lc & 7) << 4);
      af[kt] = *(const h8*)(bp + byte);
    }
    unsigned sti[4];
#pragma unroll
    for (int r = 0; r < 4; ++r) sti[r] = st_ti[p][lg * 4 + r];
    uint4 fv = {0, 0, 0, 0};
    unsigned tnx = DEADT;
    if (tid < 96) {
      tnx = st_tn[p][slot];
      if (tnx != DEADT)
        fv = *(const uint4*)(featf + ((size_t)tnx * B_ + b) * FS + ch * 8);
    }
    f32x4 acc[4];
#pragma unroll
    for (int g = 0; g < 4; ++g) acc[g] = f32x4{bias[g], bias[g], bias[g], bias[g]};
#pragma unroll
    for (int kt = 0; kt < 6; ++kt)
#pragma unroll
      for (int g = 0; g < 4; ++g)
        acc[g] = __builtin_amdgcn_mfma_f32_16x16x32_f16(af[kt], bf[g][kt],
                                                        acc[g], 0, 0, 0);
    char* bn = abuf[p ^ 1];
#pragma unroll
    for (int r = 0; r < 4; ++r) {
      const int row = lg * 4 + r;
      const float gi = sigf(acc[0][r]);
      const float gf = sigf(acc[1][r]);
      const float gg = tanhf_(acc[2][r]);
      const float go = sigf(acc[3][r]);
      const float cn = fmaf(gf, creg[r], gi * gg);
      const float hv = go * tanhf_(cn);
      const unsigned w = sti[r];
      const unsigned tt = w & 0xFFFFu;
      const bool tr = (w >> 16) != 0u;
      creg[r] = tr ? 0.0f : cn;
      *(_Float16*)(bn + ((row * 384 + 2 * d) ^ ((row & 7) << 4))) =
          (_Float16)(tr ? 0.0f : hv);
      if (tt != DEADT) hidh[((size_t)tt * B_ + b) * D_ + d] = (_Float16)hv;
    }
    if (tid < 96 && tnx != DEADT) {
      const int byte = (slot * 384 + 256 + ch * 16) ^ ((slot & 7) << 4);
      *(uint4*)(bn + byte) = fv;
    }
    {
      bool active = false;
      if (tid < 16) {
        const unsigned t_pub = t_nx;
        const unsigned trp = (t_pub == DEADT || rem_nx == 1) ? 1u : 0u;
        unsigned tn2;
        if (t_pub == DEADT) tn2 = DEADT;
        else if (rem_nx > 1) tn2 = t_pub + 1;
        else tn2 = (qw == 0xFFFFFFFFu) ? DEADT : (qw & 1023u);
        st_ti[p ^ 1][tid] = t_pub | (trp << 16);
        st_tn[p ^ 1][tid] = tn2;
        active = (t_pub != DEADT);
        if (t_pub != DEADT) {
          if (rem_nx > 1) { t_nx = t_pub + 1; rem_nx = rem_nx - 1; }
          else if (qw == 0xFFFFFFFFu) t_nx = DEADT;
          else {
            t_nx = qw & 1023u; rem_nx = (qw >> 10) & 2047u;
            qw = (qidx < qn) ? qbase[qidx] : 0xFFFFFFFFu;
            if (qidx < qn) ++qidx;
          }
        }
      }
      unsigned long long bal = __ballot(active);
      if (tid == 0) st_any[p ^ 1] = ((bal & 0xFFFFull) != 0ull) ? 1 : 0;
    }
    asm volatile("s_waitcnt lgkmcnt(0)" ::: "memory");
    __builtin_amdgcn_s_barrier();
    p ^= 1;
  }
}

// ---------------- heads: MFMA GEMM [N,128] @ [128,32], cols 0-21 valid ----------------
__global__ __launch_bounds__(256) void head_kernel(const _Float16* hidh,
                                                   const _Float16* w22,
                                                   const float* b22, float* out) {
  const int tid = threadIdx.x;
  const int w = tid >> 6, l = tid & 63;
  const int lr = l & 15, lg = l >> 4;
  const int row0 = blockIdx.x * 64 + w * 16;

  h8 bfr[2][4];
#pragma unroll
  for (int ct = 0; ct < 2; ++ct)
#pragma unroll
    for (int kt = 0; kt < 4; ++kt)
      bfr[ct][kt] = *(const h8*)(w22 + (ct * 16 + lr) * 128 + kt * 32 + lg * 8);
  h8 af[4];
#pragma unroll
  for (int kt = 0; kt < 4; ++kt)
    af[kt] = *(const h8*)(hidh + (size_t)(row0 + lr) * D_ + kt * 32 + lg * 8);

  f32x4 acc[2];
#pragma unroll
  for (int ct = 0; ct < 2; ++ct) acc[ct] = f32x4{0.f, 0.f, 0.f, 0.f};
#pragma unroll
  for (int kt = 0; kt < 4; ++kt)
#pragma unroll
    for (int ct = 0; ct < 2; ++ct)
      acc[ct] = __builtin_amdgcn_mfma_f32_16x16x32_f16(af[kt], bfr[ct][kt],
                                                       acc[ct], 0, 0, 0);
#pragma unroll
  for (int ct = 0; ct < 2; ++ct) {
    const int col = ct * 16 + lr;
    if (col < 22) {
      const float bb = b22[col];
#pragma unroll
      for (int r = 0; r < 4; ++r) {
        const int row = row0 + lg * 4 + r;
        out[(size_t)row * 22 + col] = acc[ct][r] + bb;
      }
    }
  }
}

extern "C" void kernel_launch(void* const* d_in, const int* in_sizes, int n_in,
                              void* d_out, int out_size, void* d_ws, size_t ws_size,
                              hipStream_t stream) {
  const float* image = (const float*)d_in[0];
  const float* location = (const float*)d_in[1];
  const int* message = (const int*)d_in[2];
  const float* done = (const float*)d_in[3];
  const float* h0 = (const float*)d_in[4];
  const float* c0 = (const float*)d_in[5];
  const float* vW1 = (const float*)d_in[6];
  const float* vb1 = (const float*)d_in[7];
  const float* vW2 = (const float*)d_in[8];
  const float* vb2 = (const float*)d_in[9];
  const float* vW3 = (const float*)d_in[10];
  const float* vb3 = (const float*)d_in[11];
  const float* vW4 = (const float*)d_in[12];
  const float* vb4 = (const float*)d_in[13];
  const float* locW = (const float*)d_in[14];
  const float* locb = (const float*)d_in[15];
  const float* emb = (const float*)d_in[16];
  const float* msgW = (const float*)d_in[17];
  const float* msgb = (const float*)d_in[18];
  const float* Wih = (const float*)d_in[19];
  const float* Whh = (const float*)d_in[20];
  const float* bih = (const float*)d_in[21];
  const float* bhh = (const float*)d_in[22];
  const float* aW = (const float*)d_in[23];
  const float* ab = (const float*)d_in[24];
  const float* hW = (const float*)d_in[25];
  const float* hb = (const float*)d_in[26];
  const float* cW = (const float*)d_in[27];
  const float* cb = (const float*)d_in[28];

  char* ws = (char*)d_ws;
  size_t off = 0;
  auto alloc = [&](size_t bytes) {
    void* p = ws + off;
    off = (off + bytes + 255) & ~(size_t)255;
    return p;
  };
  _Float16* featf = (_Float16*)alloc((size_t)N_ * FS * 2);   // 25.2 MB
  _Float16* hidh = (_Float16*)alloc((size_t)N_ * D_ * 2);    // 67.1 MB
  u16* w1p = (u16*)alloc(256 * 32 * 2);
  u16* w2b = (u16*)alloc(256 * 256 * 2);
  u16* w3b = (u16*)alloc(128 * 256 * 2);
  u16* w4b = (u16*)alloc(16 * 128 * 2);
  float* msgtab = (float*)alloc(256 * 4);
  _Float16* wfull = (_Float16*)alloc(512 * 192 * 2);
  float* biass = (float*)alloc(512 * 4);
  unsigned* segq = (unsigned*)alloc((size_t)B_ * 16 * SEGCAP * 4);  // 2.6 MB
  int* nqA = (int*)alloc(B_ * 16 * 4);
  _Float16* w22 = (_Float16*)alloc(32 * 128 * 2);
  float* b22 = (float*)alloc(32 * 4);
  (void)in_sizes; (void)n_in; (void)out_size; (void)ws_size;

  prep_kernel<<<64, 256, 0, stream>>>(vW1, vW2, vW3, vW4, emb, msgW, msgb, Wih,
                                      Whh, bih, bhh, aW, ab, hW, hb, cW, cb, w1p,
                                      w2b, w3b, w4b, msgtab, wfull, biass, w22,
                                      b22);
  seg_scan_kernel<<<B_, 64, 0, stream>>>(done, segq, nqA);
  enc_kernel<<<N_ / 64, 256, 0, stream>>>(image, location, message, vb1, vb2, vb3,
                                          vb4, locW, locb, w1p, w2b, w3b, w4b,
                                          msgtab, featf);
  lstm_seg_kernel<<<B_, 512, 0, stream>>>(featf, wfull, biass, segq, nqA, h0, c0,
                                          done, hidh);
  head_kernel<<<N_ / 64, 256, 0, stream>>>(hidh, w22, b22, (float*)d_out);
}